// Round 1
// baseline (98.065 us; speedup 1.0000x reference)
//
#include <hip/hip_runtime.h>
#include <math.h>

// Problem constants (match reference setup_inputs)
#define BB 4
#define NN 16384
#define MM 2048
#define BM (BB*MM)      // 8192
#define BN (BB*NN)      // 65536
#define CHUNK 512       // targets staged in LDS per block

// Workspace layout (float/uint words):
// [0, BM)          : d_smp_org running min (uint bits of nonneg float)
// [BM, BM+BN)      : d_org_smp running min
// [ACCOFF, +9)     : 0=sum_smp 1..4=per-batch max (uint bits) 5=sum_org
//                    6=trans_sum 7=rot_sum 8=cls_sum
#define ACCOFF (BM+BN)
#define WS_FLOATS (ACCOFF+9)

__global__ __launch_bounds__(256) void k_init(unsigned int* __restrict__ ws) {
    int i = blockIdx.x * 256 + threadIdx.x;
    if (i < ACCOFF) ws[i] = 0x7F800000u;          // +inf
    else if (i < WS_FLOATS) ws[i] = 0u;           // 0.0f / uint 0
}

// One kernel, both NN directions.
// blocks [0,256):  queries = sample_xyz (BM), targets = xyz chunks (32 chunks of 512)
// blocks [256,512): queries = xyz (BN), targets = sample_xyz chunks (4 chunks of 512)
// Each block: 1024 queries (4/thread, stride-256), one 512-target chunk in LDS.
// Per target float4 = (-2x,-2y,-2z, x^2+y^2+z^2); d' = fma chain; true d = d' + qsq.
__global__ __launch_bounds__(256) void k_min(const float* __restrict__ xyz,
                                             const float* __restrict__ smp,
                                             unsigned int* __restrict__ ws) {
    __shared__ float4 tgt[CHUNK];
    const int tid = threadIdx.x;
    const int bx  = blockIdx.x;
    const float* qptr;
    const float* tptr;
    unsigned int* outp;
    if (bx < 256) {
        int qb = bx >> 5;                 // 8 query-blocks (1024 queries each)
        int nc = bx & 31;                 // 32 target chunks over N
        int b  = qb >> 1;
        int qbase = b * MM + (qb & 1) * 1024;
        qptr = smp + (size_t)qbase * 3;
        tptr = xyz + (size_t)(b * NN + nc * CHUNK) * 3;
        outp = ws + qbase;
    } else {
        int bx2 = bx - 256;
        int qb = bx2 >> 2;                // 64 query-blocks
        int mc = bx2 & 3;                 // 4 target chunks over M
        int b  = qb >> 4;
        int qbase = b * NN + (qb & 15) * 1024;
        qptr = xyz + (size_t)qbase * 3;
        tptr = smp + (size_t)(b * MM + mc * CHUNK) * 3;
        outp = ws + BM + qbase;
    }
    for (int p = tid; p < CHUNK; p += 256) {
        float x = tptr[3*p+0], y = tptr[3*p+1], z = tptr[3*p+2];
        tgt[p] = make_float4(-2.0f*x, -2.0f*y, -2.0f*z, x*x + y*y + z*z);
    }
    float qx[4], qy[4], qz[4], qsq[4], mn[4];
#pragma unroll
    for (int k = 0; k < 4; ++k) {
        int q = tid + k * 256;
        qx[k] = qptr[3*q+0]; qy[k] = qptr[3*q+1]; qz[k] = qptr[3*q+2];
        qsq[k] = qx[k]*qx[k] + qy[k]*qy[k] + qz[k]*qz[k];
        mn[k] = INFINITY;
    }
    __syncthreads();
#pragma unroll 4
    for (int j = 0; j < CHUNK; ++j) {
        float4 t = tgt[j];
#pragma unroll
        for (int k = 0; k < 4; ++k) {
            float d = fmaf(t.x, qx[k], fmaf(t.y, qy[k], fmaf(t.z, qz[k], t.w)));
            mn[k] = fminf(mn[k], d);
        }
    }
#pragma unroll
    for (int k = 0; k < 4; ++k) {
        float v = fmaxf(mn[k] + qsq[k], 0.0f);   // nonneg => uint-bits order == float order
        atomicMin(outp + tid + k * 256, __float_as_uint(v));
    }
}

__device__ __forceinline__ float blockSum256(float v, volatile float* s4) {
#pragma unroll
    for (int o = 32; o > 0; o >>= 1) v += __shfl_down(v, o, 64);
    int lane = threadIdx.x & 63, w = threadIdx.x >> 6;
    if (lane == 0) s4[w] = v;
    __syncthreads();
    return s4[0] + s4[1] + s4[2] + s4[3];
}

__device__ __forceinline__ float blockMax256(float v, volatile float* s4) {
#pragma unroll
    for (int o = 32; o > 0; o >>= 1) v = fmaxf(v, __shfl_down(v, o, 64));
    int lane = threadIdx.x & 63, w = threadIdx.x >> 6;
    if (lane == 0) s4[w] = v;
    __syncthreads();
    return fmaxf(fmaxf(s4[0], s4[1]), fmaxf(s4[2], s4[3]));
}

// blocks [0,32): d_smp_org sum + per-batch max
// blocks [32,288): d_org_smp sum
// blocks [288,320): grasp reg + cls terms
__global__ __launch_bounds__(256) void k_reduce(const float* __restrict__ gp,
                                                const float* __restrict__ gg,
                                                const float* __restrict__ cp,
                                                const float* __restrict__ cg,
                                                unsigned int* __restrict__ ws) {
    __shared__ float s4a[4], s4b[4], s4c[4];
    float* wsf = (float*)ws;
    float* acc = wsf + ACCOFF;
    int bx = blockIdx.x, tid = threadIdx.x;
    if (bx < 32) {
        int i = bx * 256 + tid;
        float v = wsf[i];
        float s  = blockSum256(v, s4a);
        float mx = blockMax256(v, s4b);
        if (tid == 0) {
            atomicAdd(&acc[0], s);
            atomicMax((unsigned int*)acc + 1 + (bx >> 3), __float_as_uint(mx));
        }
    } else if (bx < 288) {
        int i = (bx - 32) * 256 + tid;
        float v = wsf[BM + i];
        float s = blockSum256(v, s4a);
        if (tid == 0) atomicAdd(&acc[5], s);
    } else {
        int m = (bx - 288) * 256 + tid;          // [0, 8192)
        const float* g = gp + (size_t)m * 7;
        float cxp = g[0], cyp = g[1], czp = g[2];
        float q0 = g[3], q1 = g[4], q2 = g[5], q3 = g[6];
        float invq = 1.0f / sqrtf(q0*q0 + q1*q1 + q2*q2 + q3*q3 + 1e-12f);
        const float* G = gg + (size_t)m * 16;
        float tr = G[0] + G[5] + G[10];
        float w = 0.5f * sqrtf(fmaxf(1.0f + tr, 1e-12f));
        float inv4w = 1.0f / (4.0f * w);
        float gqx = (G[9] - G[6]) * inv4w;       // R[2][1]-R[1][2]
        float gqy = (G[2] - G[8]) * inv4w;       // R[0][2]-R[2][0]
        float gqz = (G[4] - G[1]) * inv4w;       // R[1][0]-R[0][1]
        float cw = cg[m];
        float dx = cxp - G[3]  + 1e-6f;
        float dy = cyp - G[7]  + 1e-6f;
        float dz = czp - G[11] + 1e-6f;
        float dist = sqrtf(dx*dx + dy*dy + dz*dz);
        float dot = (q0*w + q1*gqx + q2*gqy + q3*gqz) * invq;
        float rot = acosf(fminf(fabsf(dot), 1.0f - 1e-7f));
        float p = fminf(fmaxf(cp[m], 1e-7f), 1.0f - 1e-7f);
        float ce = cw * logf(p) + (1.0f - cw) * logf(1.0f - p);
        float s1 = blockSum256(dist * cw, s4a);
        float s2 = blockSum256(rot  * cw, s4b);
        float s3 = blockSum256(ce, s4c);
        if (tid == 0) {
            atomicAdd(&acc[6], s1);
            atomicAdd(&acc[7], s2);
            atomicAdd(&acc[8], s3);
        }
    }
}

// GAMMA=0.5 ALPHA=0.5 BETA=1 THETA=1
__global__ void k_final(const float* __restrict__ temp,
                        unsigned int* __restrict__ ws,
                        float* __restrict__ out) {
    float* acc = (float*)ws + ACCOFF;
    float sample = acc[0] * (1.0f / BM)
                 + (acc[1] + acc[2] + acc[3] + acc[4]) * 0.25f
                 + 0.5f * acc[5] * (1.0f / BN);
    float reg = acc[6] * (1.0f / BM) + 0.5f * acc[7] * (1.0f / BM);
    float cls = -acc[8] * (1.0f / BM);
    float t = temp[0];
    out[0] = sample + t * t + reg + cls;
}

extern "C" void kernel_launch(void* const* d_in, const int* in_sizes, int n_in,
                              void* d_out, int out_size, void* d_ws, size_t ws_size,
                              hipStream_t stream) {
    const float* xyz  = (const float*)d_in[0];
    const float* smp  = (const float*)d_in[1];
    const float* temp = (const float*)d_in[2];
    const float* gp   = (const float*)d_in[3];
    const float* gg   = (const float*)d_in[4];
    const float* cp   = (const float*)d_in[5];
    const float* cg   = (const float*)d_in[6];
    unsigned int* ws  = (unsigned int*)d_ws;
    float* out = (float*)d_out;

    hipLaunchKernelGGL(k_init,   dim3((WS_FLOATS + 255) / 256), dim3(256), 0, stream, ws);
    hipLaunchKernelGGL(k_min,    dim3(512), dim3(256), 0, stream, xyz, smp, ws);
    hipLaunchKernelGGL(k_reduce, dim3(320), dim3(256), 0, stream, gp, gg, cp, cg, ws);
    hipLaunchKernelGGL(k_final,  dim3(1), dim3(1), 0, stream, temp, ws, out);
}